// Round 11
// baseline (21247.446 us; speedup 1.0000x reference)
//
#include <hip/hip_runtime.h>

typedef unsigned long long u64;
typedef unsigned int u32;
typedef unsigned short u16;
typedef _Float16 f16;
typedef _Float16 h2v __attribute__((ext_vector_type(2)));

#define BB 16
#define TT 1500
#define NG3 1536
#define GM (BB * TT)   /* 24000 */
#define GK 512
#define LNEPS 1e-5f
#define NWG 48         /* WGs per role */
#define H0D 8          /* Hb0 ring depth */
#define H1D 4          /* Hb1 ring depth */
#define HROW 256       /* u64 per h row (512 f16 + tags) */
#define GROW 768       /* u64 per gate row (1536 f16 + tags) */

// ---------------- helpers ----------------
__device__ __forceinline__ float sigmoidf_(float x) { return 1.f / (1.f + __expf(-x)); }
__device__ __forceinline__ float tanhf_(float x) {
  x = fminf(15.f, fmaxf(-15.f, x));
  float e = __expf(2.f * x);
  return (e - 1.f) / (e + 1.f);
}
__device__ __forceinline__ float red16_(float v) {
  v += __shfl_xor(v, 1, 64); v += __shfl_xor(v, 2, 64);
  v += __shfl_xor(v, 4, 64); v += __shfl_xor(v, 8, 64);
  return v;
}
__device__ __forceinline__ float red64_(float v) {
  v = red16_(v);
  v += __shfl_xor(v, 16, 64); v += __shfl_xor(v, 32, 64);
  return v;
}
__device__ __forceinline__ u32 pkh2(float a, float b) {
  u16 sa = __builtin_bit_cast(u16, (f16)a);
  u16 sb = __builtin_bit_cast(u16, (f16)b);
  return (u32)sa | ((u32)sb << 16);
}
__device__ __forceinline__ float f16lo(u32 p) { u16 s = (u16)p; return (float)__builtin_bit_cast(f16, s); }
__device__ __forceinline__ float f16hi(u32 p) { u16 s = (u16)(p >> 16); return (float)__builtin_bit_cast(f16, s); }
__device__ __forceinline__ h2v bch2(u32 u) { return __builtin_bit_cast(h2v, u); }
__device__ __forceinline__ float dot2f(h2v a, h2v b, float c) {
#if __has_builtin(__builtin_amdgcn_fdot2)
  return __builtin_amdgcn_fdot2(a, b, c, false);
#else
  return fmaf((float)a.y, (float)b.y, fmaf((float)a.x, (float)b.x, c));
#endif
}
// 16B-chunk swizzle within a 64-chunk h row (2-way max on matvec reads)
__device__ __forceinline__ int physp(int c) { return c ^ ((c >> 2) & 7); }

__device__ __forceinline__ u64 ldA(const u64* p) {
  return __hip_atomic_load(p, __ATOMIC_RELAXED, __HIP_MEMORY_SCOPE_AGENT);
}
__device__ __forceinline__ void stA8(u64* p, u64 v) {
  __hip_atomic_store(p, v, __ATOMIC_RELAXED, __HIP_MEMORY_SCOPE_AGENT);
}
__device__ __forceinline__ u64 mkw(u32 tag, float a, float b) {
  return ((u64)tag << 32) | (u64)pkh2(a, b);
}

// ---------------- big GEMM: C[M,N] = A[M,K] @ W[N,K]^T (fp32) ----------------
__global__ __launch_bounds__(256) void gemm_nt(const float* __restrict__ A,
                                               const float* __restrict__ W,
                                               float* __restrict__ C) {
  __shared__ __align__(16) float As[32][68];
  __shared__ __align__(16) float Ws[32][68];
  const int m0 = blockIdx.x * 64;
  const int n0 = blockIdx.y * 64;
  const int tid = threadIdx.x;
  const int tm = tid & 15, tn = tid >> 4;
  float acc[4][4] = {};
  for (int k0 = 0; k0 < GK; k0 += 32) {
#pragma unroll
    for (int u = 0; u < 2; ++u) {
      int idx = tid + u * 256;
      int r = idx >> 3;
      int kq = (idx & 7) * 4;
      float4 a = *reinterpret_cast<const float4*>(&A[(size_t)(m0 + r) * GK + k0 + kq]);
      As[kq + 0][r] = a.x; As[kq + 1][r] = a.y; As[kq + 2][r] = a.z; As[kq + 3][r] = a.w;
      float4 w = *reinterpret_cast<const float4*>(&W[(size_t)(n0 + r) * GK + k0 + kq]);
      Ws[kq + 0][r] = w.x; Ws[kq + 1][r] = w.y; Ws[kq + 2][r] = w.z; Ws[kq + 3][r] = w.w;
    }
    __syncthreads();
#pragma unroll
    for (int kk = 0; kk < 32; ++kk) {
      float a[4], w[4];
      *reinterpret_cast<float4*>(a) = *reinterpret_cast<const float4*>(&As[kk][tm * 4]);
      *reinterpret_cast<float4*>(w) = *reinterpret_cast<const float4*>(&Ws[kk][tn * 4]);
#pragma unroll
      for (int i = 0; i < 4; ++i)
#pragma unroll
        for (int q = 0; q < 4; ++q)
          acc[i][q] = fmaf(a[i], w[q], acc[i][q]);
    }
    __syncthreads();
  }
#pragma unroll
  for (int i = 0; i < 4; ++i) {
    float4 v = make_float4(acc[i][0], acc[i][1], acc[i][2], acc[i][3]);
    *reinterpret_cast<float4*>(&C[(size_t)(m0 + tm * 4 + i) * NG3 + n0 + tn * 4]) = v;
  }
}

// ---------------- fused 2-layer GRU: tags-in-data, owner-LN, h-broadcast -----
// role 0 (WG 0..47):   L0 matvec Wh0·h0(t-1); owners (wgl<16) LN + publish h0(t)
// role 1 (WG 48..95):  L1 matvec Wh1·h1(t-1); owners LN (+resid h0(t)) + h1(t) + out
// role 2 (WG 96..143): L1 matvec Wi1·h0(t) -> G1x (r,z,x_n sections)
// ALL exchanged words are u64 = (tag=t+1)<<32 | 2xf16. Fire-and-forget stores;
// consumers poll tags on the data itself. No fences, no drains, no flags.
// Ring-overwrite safety (audited, cycle-free):
//  - G* double buffers: producer at t overwrites gates(t-2); owner published
//    h(t-1) => consumed gates(t-1) => consumed gates(t-2). Transitively safe
//    because producers only reach step t after copying h(t-1).
//  - Hb0 slot t&7 overwritten by owner-0 at t>=8: consumers of h0(t-8) are
//    role-0 WGs (at >= t-1, implied) and role-2 (implied by h1(t-8) published,
//    polled explicitly: Hb1 tag >= t-7).
//  - Hb1 slot t&3 overwritten by owner-1 at t>=4: role-1 WGs at step t did
//    matvec(t) => copied h1(t-1) => long past reading h1(t-4). Safe.
//  - G1x buffer t&1 overwritten by role-2 at t: owner-1 consumed G1x(t-2)
//    iff h1(t-2) published (polled: Hb1 tag >= t-1).
__global__ __launch_bounds__(256, 1) void gru_fused(
    const float* __restrict__ Wh0, const float* __restrict__ Wi1,
    const float* __restrict__ Wh1, const float* __restrict__ X0,
    const float* __restrict__ lnw, const float* __restrict__ lnb,
    float* __restrict__ out, u64* __restrict__ G0, u64* __restrict__ G1h,
    u64* __restrict__ G1x, u64* __restrict__ Hb0, u64* __restrict__ Hb1) {
  __shared__ __align__(16) u16 shA[BB][544];  // h copy (f16, swizzled chunks)
  __shared__ __align__(16) float red4[4][6];  // owner LN cross-wave combine

  const int tid = threadIdx.x, wg = blockIdx.x;
  const int lane = tid & 63, wave = tid >> 6;
  const int ks = lane & 15, cq = lane >> 4;
  const int role = wg / NWG;            // 0=L0, 1=L1h, 2=L1x
  const int wgl = wg - role * NWG;
  const int pairIdx = wgl * 16 + wave * 4 + cq;  // col-pair 0..767
  const int col0 = pairIdx * 2;
  const int rr = tid >> 4, q16 = tid & 15;       // h-copy assignment

  // ---- persistent weights: this role's matrix, 2 cols, f16-packed ----
  const float* Wsel = (role == 0) ? Wh0 : (role == 1) ? Wh1 : Wi1;
  u32 wp[2][16];
#pragma unroll
  for (int c = 0; c < 2; ++c) {
    const float* Wp = Wsel + (size_t)(col0 + c) * 512 + ks * 32;
#pragma unroll
    for (int i = 0; i < 16; ++i) wp[c][i] = pkh2(Wp[2 * i], Wp[2 * i + 1]);
  }
  // ---- owner setup ----
  const bool own = (role <= 1) && (wgl < 16);
  const int b_own = wgl;
  const float* lnwL = lnw + (role == 1 ? NG3 : 0);
  const float* lnbL = lnb + (role == 1 ? NG3 : 0);
  float lwv[6], lbv[6];
  if (own) {
#pragma unroll
    for (int g = 0; g < 3; ++g)
#pragma unroll
      for (int c = 0; c < 2; ++c) {
        lwv[g * 2 + c] = lnwL[g * 512 + 2 * tid + c];
        lbv[g * 2 + c] = lnbL[g * 512 + 2 * tid + c];
      }
  }
  u64* Gst = (role == 0) ? G0 : (role == 1) ? G1h : G1x;

  for (int idx = tid; idx < BB * 544; idx += 256) (&shA[0][0])[idx] = 0;
  __syncthreads();

  for (int t = 0; t < TT; ++t) {
    const u32 want = (u32)(t + 1);

    // ---- A: refresh h copy in LDS (tagged poll, 16 u64/thread) ----
    {
      const u64* src = nullptr;
      u32 wantH = 0;
      if (role == 2) {
        src = Hb0 + (size_t)(t & (H0D - 1)) * (BB * HROW);
        wantH = want;
      } else if (t > 0) {
        src = (role == 0)
            ? Hb0 + (size_t)((t - 1) & (H0D - 1)) * (BB * HROW)
            : Hb1 + (size_t)((t - 1) & (H1D - 1)) * (BB * HROW);
        wantH = (u32)t;
      }
      if (src) {
        const u64* p = src + (size_t)rr * HROW + q16 * 16;
        u32 pl[16];
        for (;;) {
          u32 bad = 0;
          u64 w[16];
#pragma unroll
          for (int m = 0; m < 16; ++m) {
            w[m] = ldA(p + m);
            bad |= (u32)(w[m] >> 32) ^ wantH;
          }
          if (!bad) {
#pragma unroll
            for (int m = 0; m < 16; ++m) pl[m] = (u32)w[m];
            break;
          }
          __builtin_amdgcn_s_sleep(1);
        }
        __syncthreads();  // all prior shA readers (matvec/owner) done
#pragma unroll
        for (int w2 = 0; w2 < 4; ++w2)
          *reinterpret_cast<uint4*>(&shA[rr][physp(q16 * 4 + w2) * 8]) =
              make_uint4(pl[4 * w2], pl[4 * w2 + 1], pl[4 * w2 + 2], pl[4 * w2 + 3]);
        __syncthreads();
      }
    }

    // ---- B: matvec (thread = (ks, col-pair); reduce over 16 lanes) ----
    float g0 = 0.f, g1 = 0.f;
#pragma unroll 4
    for (int b = 0; b < 16; ++b) {
      float p0 = 0.f, p1 = 0.f;
#pragma unroll
      for (int j = 0; j < 4; ++j) {
        const int idx = ((ks * 4 + j) ^ (ks & 7)) * 8;
        uint4 ua = *reinterpret_cast<const uint4*>(&shA[b][idx]);
        p0 = dot2f(bch2(ua.x), bch2(wp[0][j * 4 + 0]), p0);
        p0 = dot2f(bch2(ua.y), bch2(wp[0][j * 4 + 1]), p0);
        p0 = dot2f(bch2(ua.z), bch2(wp[0][j * 4 + 2]), p0);
        p0 = dot2f(bch2(ua.w), bch2(wp[0][j * 4 + 3]), p0);
        p1 = dot2f(bch2(ua.x), bch2(wp[1][j * 4 + 0]), p1);
        p1 = dot2f(bch2(ua.y), bch2(wp[1][j * 4 + 1]), p1);
        p1 = dot2f(bch2(ua.z), bch2(wp[1][j * 4 + 2]), p1);
        p1 = dot2f(bch2(ua.w), bch2(wp[1][j * 4 + 3]), p1);
      }
      p0 = red16_(p0); p1 = red16_(p1);
      if (ks == b) { g0 = p0; g1 = p1; }
    }
    // role-2 overwrite throttle: owner-1 must have consumed G1x(t-2)
    if (role == 2 && t >= 2) {
      const u32 w2 = (u32)(t - 1);  // h1(t-2) published => tag >= t-1
      const u64* hb = Hb1 + (size_t)((t - 2) & (H1D - 1)) * (BB * HROW) +
                      (size_t)(tid & 15) * HROW;
      while ((u32)(ldA(hb) >> 32) < w2) __builtin_amdgcn_s_sleep(1);
      asm volatile("" ::: "memory");
    }
    // tagged gate store — fire and forget
    stA8(&Gst[(size_t)(t & 1) * (BB * GROW) + (size_t)ks * GROW + pairIdx],
         ((u64)want << 32) | (u64)pkh2(g0, g1));

    // ---- C: owner phase (tagged gate poll + LN + h update + publish) ----
    if (own) {
      // prefetch X row (role 0; plain cached, L3-resident) before the poll
      float xr0 = 0, xr1 = 0, xz0 = 0, xz1 = 0, xpn0 = 0, xpn1 = 0;
      if (role == 0) {
        const float* Xr = X0 + ((size_t)b_own * TT + t) * NG3 + 2 * tid;
        float2 a = *reinterpret_cast<const float2*>(Xr);
        float2 b = *reinterpret_cast<const float2*>(Xr + 512);
        float2 c = *reinterpret_cast<const float2*>(Xr + 1024);
        xr0 = a.x; xr1 = a.y; xz0 = b.x; xz1 = b.y; xpn0 = c.x; xpn1 = c.y;
      }
      const u64* Gr = ((role == 0) ? G0 : G1h) +
                      (size_t)(t & 1) * (BB * GROW) + (size_t)b_own * GROW;
      const u64* Gx = G1x + (size_t)(t & 1) * (BB * GROW) + (size_t)b_own * GROW;
      float gr0, gr1, gz0, gz1, hn0, hn1, xg0, xg1;
      for (;;) {
        u32 bad = 0;
        u64 pr = ldA(&Gr[tid]);
        u64 pz = ldA(&Gr[tid + 256]);
        u64 pn = ldA(&Gr[tid + 512]);
        bad = ((u32)(pr >> 32) ^ want) | ((u32)(pz >> 32) ^ want) |
              ((u32)(pn >> 32) ^ want);
        u64 qr = 0, qz = 0, qx = 0;
        if (role == 1) {
          qr = ldA(&Gx[tid]);
          qz = ldA(&Gx[tid + 256]);
          qx = ldA(&Gx[tid + 512]);
          bad |= ((u32)(qr >> 32) ^ want) | ((u32)(qz >> 32) ^ want) |
                 ((u32)(qx >> 32) ^ want);
        }
        if (!bad) {
          gr0 = f16lo((u32)pr); gr1 = f16hi((u32)pr);
          gz0 = f16lo((u32)pz); gz1 = f16hi((u32)pz);
          hn0 = f16lo((u32)pn); hn1 = f16hi((u32)pn);
          if (role == 1) {
            gr0 += f16lo((u32)qr); gr1 += f16hi((u32)qr);
            gz0 += f16lo((u32)qz); gz1 += f16hi((u32)qz);
            xg0 = f16lo((u32)qx); xg1 = f16hi((u32)qx);
          } else {
            gr0 += xr0; gr1 += xr1; gz0 += xz0; gz1 += xz1;
            xg0 = xpn0; xg1 = xpn1;
          }
          break;
        }
        __builtin_amdgcn_s_sleep(1);
      }
      // LN r & z (one cross-wave combine)
      float sr = red64_(gr0 + gr1), sr2 = red64_(gr0 * gr0 + gr1 * gr1);
      float sz = red64_(gz0 + gz1), sz2 = red64_(gz0 * gz0 + gz1 * gz1);
      if (lane == 0) {
        red4[wave][0] = sr; red4[wave][1] = sr2;
        red4[wave][2] = sz; red4[wave][3] = sz2;
      }
      __syncthreads();
      float tsr = 0, tsr2 = 0, tsz = 0, tsz2 = 0;
#pragma unroll
      for (int w = 0; w < 4; ++w) {
        tsr += red4[w][0]; tsr2 += red4[w][1];
        tsz += red4[w][2]; tsz2 += red4[w][3];
      }
      const float mr = tsr * (1.f / 512.f);
      const float rsr = rsqrtf(tsr2 * (1.f / 512.f) - mr * mr + LNEPS);
      const float mz = tsz * (1.f / 512.f);
      const float rsz = rsqrtf(tsz2 * (1.f / 512.f) - mz * mz + LNEPS);
      const float rv0 = sigmoidf_((gr0 - mr) * rsr * lwv[0] + lbv[0]);
      const float rv1 = sigmoidf_((gr1 - mr) * rsr * lwv[1] + lbv[1]);
      const float zv0 = sigmoidf_((gz0 - mz) * rsz * lwv[2] + lbv[2]);
      const float zv1 = sigmoidf_((gz1 - mz) * rsz * lwv[3] + lbv[3]);
      // LN n (second combine, disjoint red4 slots)
      const float np0 = xg0 + rv0 * hn0;
      const float np1 = xg1 + rv1 * hn1;
      float sn = red64_(np0 + np1), sn2 = red64_(np0 * np0 + np1 * np1);
      if (lane == 0) { red4[wave][4] = sn; red4[wave][5] = sn2; }
      __syncthreads();
      float tn = red4[0][4] + red4[1][4] + red4[2][4] + red4[3][4];
      float tn2 = red4[0][5] + red4[1][5] + red4[2][5] + red4[3][5];
      const float mn = tn * (1.f / 512.f);
      const float rsn = rsqrtf(tn2 * (1.f / 512.f) - mn * mn + LNEPS);
      // h update (hold from local LDS copy = h(t-1))
      u32 hp = *reinterpret_cast<const u32*>(
          &shA[b_own][physp(tid >> 2) * 8 + 2 * (tid & 3)]);
      const float n0 = tanhf_((np0 - mn) * rsn * lwv[4] + lbv[4]);
      const float n1 = tanhf_((np1 - mn) * rsn * lwv[5] + lbv[5]);
      float hv0 = (1.f - zv0) * n0 + zv0 * f16lo(hp);
      float hv1 = (1.f - zv1) * n1 + zv1 * f16hi(hp);
      if (role == 1) {  // residual h0(t) (tags necessarily set: G1x(t) existed)
        const u64* Hr = Hb0 + (size_t)(t & (H0D - 1)) * (BB * HROW) +
                        (size_t)b_own * HROW + tid;
        u64 w;
        while ((u32)((w = ldA(Hr)) >> 32) != want) __builtin_amdgcn_s_sleep(1);
        hv0 += f16lo((u32)w); hv1 += f16hi((u32)w);
        *reinterpret_cast<float2*>(&out[((size_t)b_own * TT + t) * 512 + 2 * tid]) =
            make_float2(hv0, hv1);
      }
      // owner-0 ring throttle: role-2 must have consumed h0(t-8)
      if (role == 0 && t >= H0D) {
        const u32 w2 = (u32)(t - (H0D - 1));  // h1(t-8) published => tag >= t-7
        const u64* hb = Hb1 + (size_t)((t - H0D) & (H1D - 1)) * (BB * HROW) +
                        (size_t)(tid & 15) * HROW;
        while ((u32)(ldA(hb) >> 32) < w2) __builtin_amdgcn_s_sleep(1);
        asm volatile("" ::: "memory");
      }
      // publish tagged h row — fire and forget
      u64* Hw = ((role == 0)
                     ? Hb0 + (size_t)(t & (H0D - 1)) * (BB * HROW)
                     : Hb1 + (size_t)(t & (H1D - 1)) * (BB * HROW)) +
                (size_t)b_own * HROW;
      stA8(&Hw[tid], ((u64)want << 32) | (u64)pkh2(hv0, hv1));
    }
  }
}

// ---------------- launch ----------------
extern "C" void kernel_launch(void* const* d_in, const int* in_sizes, int n_in,
                              void* d_out, int out_size, void* d_ws, size_t ws_size,
                              hipStream_t stream) {
  (void)in_sizes; (void)n_in; (void)out_size; (void)ws_size;
  const float* x   = (const float*)d_in[0];
  const float* Wi  = (const float*)d_in[1];  // [2][1536][512]
  const float* Wh  = (const float*)d_in[2];  // [2][1536][512]
  const float* lnw = (const float*)d_in[3];  // [2][3][512]
  const float* lnb = (const float*)d_in[4];
  float* out = (float*)d_out;

  float* X0 = (float*)d_ws;                     // [24000][1536] f32
  u64* G0   = (u64*)(X0 + (size_t)GM * NG3);    // [2][16][768]
  u64* G1h  = G0 + 2 * BB * GROW;               // [2][16][768]
  u64* G1x  = G1h + 2 * BB * GROW;              // [2][16][768]
  u64* Hb0  = G1x + 2 * BB * GROW;              // [8][16][256]
  u64* Hb1  = Hb0 + (size_t)H0D * BB * HROW;    // [4][16][256]

  size_t clear_bytes = (size_t)(3 * 2 * BB * GROW + H0D * BB * HROW +
                                H1D * BB * HROW) * 8;
  hipMemsetAsync(G0, 0, clear_bytes, stream);

  dim3 ggrid(GM / 64, NG3 / 64);
  gemm_nt<<<ggrid, 256, 0, stream>>>(x, Wi, X0);  // layer-0 input gates
  gru_fused<<<3 * NWG, 256, 0, stream>>>(
      Wh, Wi + (size_t)NG3 * 512, Wh + (size_t)NG3 * 512, X0, lnw, lnb, out,
      G0, G1h, G1x, Hb0, Hb1);
}

// Round 12
// 15738.213 us; speedup vs baseline: 1.3501x; 1.3501x over previous
//
#include <hip/hip_runtime.h>

typedef unsigned long long u64;
typedef unsigned int u32;
typedef unsigned short u16;
typedef _Float16 f16;
typedef _Float16 h2v __attribute__((ext_vector_type(2)));

#define BB 16
#define TT 1500
#define NG3 1536
#define GM (BB * TT)   /* 24000 */
#define GK 512
#define LNEPS 1e-5f
#define NWG 48         /* WGs per role */
#define FL 64          /* flag line stride in u32 (256B) */
#define H0D 8          /* Hb0 ring depth */
#define H1D 4          /* Hb1 ring depth */
#define HROWU 256      /* u32 per h row (512 f16) */
#define GROW 768       /* u64 per gate row (1536 f16 + tags) */

// ---------------- helpers ----------------
__device__ __forceinline__ float sigmoidf_(float x) { return 1.f / (1.f + __expf(-x)); }
__device__ __forceinline__ float tanhf_(float x) {
  x = fminf(15.f, fmaxf(-15.f, x));
  float e = __expf(2.f * x);
  return (e - 1.f) / (e + 1.f);
}
__device__ __forceinline__ float red16_(float v) {
  v += __shfl_xor(v, 1, 64); v += __shfl_xor(v, 2, 64);
  v += __shfl_xor(v, 4, 64); v += __shfl_xor(v, 8, 64);
  return v;
}
__device__ __forceinline__ float red64_(float v) {
  v = red16_(v);
  v += __shfl_xor(v, 16, 64); v += __shfl_xor(v, 32, 64);
  return v;
}
__device__ __forceinline__ u32 pkh2(float a, float b) {
  u16 sa = __builtin_bit_cast(u16, (f16)a);
  u16 sb = __builtin_bit_cast(u16, (f16)b);
  return (u32)sa | ((u32)sb << 16);
}
__device__ __forceinline__ float f16lo(u32 p) { u16 s = (u16)p; return (float)__builtin_bit_cast(f16, s); }
__device__ __forceinline__ float f16hi(u32 p) { u16 s = (u16)(p >> 16); return (float)__builtin_bit_cast(f16, s); }
__device__ __forceinline__ h2v bch2(u32 u) { return __builtin_bit_cast(h2v, u); }
__device__ __forceinline__ float dot2f(h2v a, h2v b, float c) {
#if __has_builtin(__builtin_amdgcn_fdot2)
  return __builtin_amdgcn_fdot2(a, b, c, false);
#else
  return fmaf((float)a.y, (float)b.y, fmaf((float)a.x, (float)b.x, c));
#endif
}
// 16B-chunk swizzle within a 64-chunk h row (2-way max on matvec reads)
__device__ __forceinline__ int physp(int c) { return c ^ ((c >> 2) & 7); }

__device__ __forceinline__ u64 ldA(const u64* p) {
  return __hip_atomic_load(p, __ATOMIC_RELAXED, __HIP_MEMORY_SCOPE_AGENT);
}
__device__ __forceinline__ void stA8(u64* p, u64 v) {
  __hip_atomic_store(p, v, __ATOMIC_RELAXED, __HIP_MEMORY_SCOPE_AGENT);
}
__device__ __forceinline__ u32 ldA32(const u32* p) {
  return __hip_atomic_load(p, __ATOMIC_RELAXED, __HIP_MEMORY_SCOPE_AGENT);
}
__device__ __forceinline__ void stA32(u32* p, u32 v) {
  __hip_atomic_store(p, v, __ATOMIC_RELAXED, __HIP_MEMORY_SCOPE_AGENT);
}

// ---------------- big GEMM: C[M,N] = A[M,K] @ W[N,K]^T (fp32) ----------------
__global__ __launch_bounds__(256) void gemm_nt(const float* __restrict__ A,
                                               const float* __restrict__ W,
                                               float* __restrict__ C) {
  __shared__ __align__(16) float As[32][68];
  __shared__ __align__(16) float Ws[32][68];
  const int m0 = blockIdx.x * 64;
  const int n0 = blockIdx.y * 64;
  const int tid = threadIdx.x;
  const int tm = tid & 15, tn = tid >> 4;
  float acc[4][4] = {};
  for (int k0 = 0; k0 < GK; k0 += 32) {
#pragma unroll
    for (int u = 0; u < 2; ++u) {
      int idx = tid + u * 256;
      int r = idx >> 3;
      int kq = (idx & 7) * 4;
      float4 a = *reinterpret_cast<const float4*>(&A[(size_t)(m0 + r) * GK + k0 + kq]);
      As[kq + 0][r] = a.x; As[kq + 1][r] = a.y; As[kq + 2][r] = a.z; As[kq + 3][r] = a.w;
      float4 w = *reinterpret_cast<const float4*>(&W[(size_t)(n0 + r) * GK + k0 + kq]);
      Ws[kq + 0][r] = w.x; Ws[kq + 1][r] = w.y; Ws[kq + 2][r] = w.z; Ws[kq + 3][r] = w.w;
    }
    __syncthreads();
#pragma unroll
    for (int kk = 0; kk < 32; ++kk) {
      float a[4], w[4];
      *reinterpret_cast<float4*>(a) = *reinterpret_cast<const float4*>(&As[kk][tm * 4]);
      *reinterpret_cast<float4*>(w) = *reinterpret_cast<const float4*>(&Ws[kk][tn * 4]);
#pragma unroll
      for (int i = 0; i < 4; ++i)
#pragma unroll
        for (int q = 0; q < 4; ++q)
          acc[i][q] = fmaf(a[i], w[q], acc[i][q]);
    }
    __syncthreads();
  }
#pragma unroll
  for (int i = 0; i < 4; ++i) {
    float4 v = make_float4(acc[i][0], acc[i][1], acc[i][2], acc[i][3]);
    *reinterpret_cast<float4*>(&C[(size_t)(m0 + tm * 4 + i) * NG3 + n0 + tn * 4]) = v;
  }
}

// ---------------- fused 2-layer GRU: tagged gates + flagged h broadcast ------
// role 0 (WG 0..47):   L0 matvec Wh0·h0(t-1); owners (wgl<16) LN + publish h0(t)
// role 1 (WG 48..95):  L1 matvec Wh1·h1(t-1); owners LN (+resid h0(t)) + h1 + out
// role 2 (WG 96..143): L1 matvec Wi1·h0(t) -> G1x (r,z,x_n sections)
// Gates: u64 = (tag=t+1)<<32 | 2xf16. Fire-and-forget; owner polls its own row.
// h rows: untagged u32 f16-pairs; producer drains vmcnt(0) then sets row flag;
// consumers per-thread poll their row's flag, then bulk-copy once.
// Ring/overwrite safety (cycle-free):
//  - G0/G1h dbuf: producer at t overwrites gates(t-2); producers only reach t
//    after copying h(t-1), whose publication implies gates(t-1) (hence t-2)
//    consumed. Safe transitively.
//  - G1x dbuf: thread stores row ks at t only after h1f[ks] >= t-1 (owner-1(ks)
//    published h1(t-2) => consumed G1x(t-2) row ks). Exact, per-thread.
//  - Hb0 slot t&7 (t>=8): ANY h1f[b] >= t-7 => owner-1(b) consumed G1x(t-8)
//    => all 48 role-2 WGs stored step t-8 => all completed their h0(t-8) copy.
//    Per-thread poll h1f[tid&15], no barrier needed.
//  - Hb1 slot t&3: role-1 WGs at step t copied h1(t-1), far past h1(t-4). Safe.
__global__ __launch_bounds__(256, 1) void gru_fused(
    const float* __restrict__ Wh0, const float* __restrict__ Wi1,
    const float* __restrict__ Wh1, const float* __restrict__ X0,
    const float* __restrict__ lnw, const float* __restrict__ lnb,
    float* __restrict__ out, u64* __restrict__ G0, u64* __restrict__ G1h,
    u64* __restrict__ G1x, u32* __restrict__ Hb0, u32* __restrict__ Hb1,
    u32* __restrict__ flags) {
  u32* h0f = flags;             // [16] h0 row flags
  u32* h1f = flags + 16 * FL;   // [16] h1 row flags

  __shared__ __align__(16) u16 shA[BB][544];  // h copy (f16, swizzled chunks)
  __shared__ __align__(16) float red4[4][6];  // owner LN cross-wave combine

  const int tid = threadIdx.x, wg = blockIdx.x;
  const int lane = tid & 63, wave = tid >> 6;
  const int ks = lane & 15, cq = lane >> 4;
  const int role = wg / NWG;            // 0=L0, 1=L1h, 2=L1x
  const int wgl = wg - role * NWG;
  const int pairIdx = wgl * 16 + wave * 4 + cq;  // col-pair 0..767
  const int col0 = pairIdx * 2;
  const int rr = tid >> 4, q16 = tid & 15;       // h-copy assignment

  // ---- persistent weights: this role's matrix, 2 cols, f16-packed ----
  const float* Wsel = (role == 0) ? Wh0 : (role == 1) ? Wh1 : Wi1;
  u32 wp[2][16];
#pragma unroll
  for (int c = 0; c < 2; ++c) {
    const float* Wp = Wsel + (size_t)(col0 + c) * 512 + ks * 32;
#pragma unroll
    for (int i = 0; i < 16; ++i) wp[c][i] = pkh2(Wp[2 * i], Wp[2 * i + 1]);
  }
  // ---- owner setup ----
  const bool own = (role <= 1) && (wgl < 16);
  const int b_own = wgl;
  const float* lnwL = lnw + (role == 1 ? NG3 : 0);
  const float* lnbL = lnb + (role == 1 ? NG3 : 0);
  float lwv[6], lbv[6];
  if (own) {
#pragma unroll
    for (int g = 0; g < 3; ++g)
#pragma unroll
      for (int c = 0; c < 2; ++c) {
        lwv[g * 2 + c] = lnwL[g * 512 + 2 * tid + c];
        lbv[g * 2 + c] = lnbL[g * 512 + 2 * tid + c];
      }
  }
  u64* Gst = (role == 0) ? G0 : (role == 1) ? G1h : G1x;

  for (int idx = tid; idx < BB * 544; idx += 256) (&shA[0][0])[idx] = 0;
  __syncthreads();

  for (int t = 0; t < TT; ++t) {
    const u32 want = (u32)(t + 1);

    // ---- A: refresh h copy in LDS (per-thread row-flag poll + bulk copy) ----
    if (role == 2 || t > 0) {
      __syncthreads();  // all prior shA readers (matvec / owner hold) done
      const u32 wantH = (role == 2) ? want : (u32)t;
      const u32* hf = (role == 1) ? h1f : h0f;
      while (ldA32(&hf[(size_t)rr * FL]) < wantH) __builtin_amdgcn_s_sleep(1);
      const u32* Hsrc = (role == 1)
          ? Hb1 + (size_t)((t - 1) & (H1D - 1)) * (BB * HROWU)
          : (role == 0)
              ? Hb0 + (size_t)((t - 1) & (H0D - 1)) * (BB * HROWU)
              : Hb0 + (size_t)(t & (H0D - 1)) * (BB * HROWU);
      const u64* src = (const u64*)(Hsrc + (size_t)rr * HROWU) + q16 * 8;
      u32 pl[16];
#pragma unroll
      for (int m = 0; m < 8; ++m) {
        u64 w = ldA(src + m);
        pl[2 * m] = (u32)w; pl[2 * m + 1] = (u32)(w >> 32);
      }
#pragma unroll
      for (int w2 = 0; w2 < 4; ++w2)
        *reinterpret_cast<uint4*>(&shA[rr][physp(q16 * 4 + w2) * 8]) =
            make_uint4(pl[4 * w2], pl[4 * w2 + 1], pl[4 * w2 + 2], pl[4 * w2 + 3]);
      __syncthreads();
    }

    // ---- B: matvec (thread = (ks, col-pair); reduce over 16 lanes) ----
    float g0 = 0.f, g1 = 0.f;
#pragma unroll 4
    for (int b = 0; b < 16; ++b) {
      float p0 = 0.f, p1 = 0.f;
#pragma unroll
      for (int j = 0; j < 4; ++j) {
        const int idx = ((ks * 4 + j) ^ (ks & 7)) * 8;
        uint4 ua = *reinterpret_cast<const uint4*>(&shA[b][idx]);
        p0 = dot2f(bch2(ua.x), bch2(wp[0][j * 4 + 0]), p0);
        p0 = dot2f(bch2(ua.y), bch2(wp[0][j * 4 + 1]), p0);
        p0 = dot2f(bch2(ua.z), bch2(wp[0][j * 4 + 2]), p0);
        p0 = dot2f(bch2(ua.w), bch2(wp[0][j * 4 + 3]), p0);
        p1 = dot2f(bch2(ua.x), bch2(wp[1][j * 4 + 0]), p1);
        p1 = dot2f(bch2(ua.y), bch2(wp[1][j * 4 + 1]), p1);
        p1 = dot2f(bch2(ua.z), bch2(wp[1][j * 4 + 2]), p1);
        p1 = dot2f(bch2(ua.w), bch2(wp[1][j * 4 + 3]), p1);
      }
      p0 = red16_(p0); p1 = red16_(p1);
      if (ks == b) { g0 = p0; g1 = p1; }
    }
    // role-2 overwrite throttle (per-thread, exact): owner-1(ks) done with
    // G1x(t-2) row ks <=> h1(t-2) published <=> h1f[ks] >= t-1
    if (role == 2 && t >= 2) {
      const u32 w2 = (u32)(t - 1);
      while (ldA32(&h1f[(size_t)ks * FL]) < w2) __builtin_amdgcn_s_sleep(1);
    }
    // tagged gate store — fire and forget (no drain, no barrier, no flag)
    stA8(&Gst[(size_t)(t & 1) * (BB * GROW) + (size_t)ks * GROW + pairIdx],
         ((u64)want << 32) | (u64)pkh2(g0, g1));

    // ---- C: owner phase (tagged gate poll + LN + h update + publish) ----
    if (own) {
      // prefetch X row (role 0; plain cached, L3-resident) before the poll
      float xr0 = 0, xr1 = 0, xz0 = 0, xz1 = 0, xpn0 = 0, xpn1 = 0;
      if (role == 0) {
        const float* Xr = X0 + ((size_t)b_own * TT + t) * NG3 + 2 * tid;
        float2 a = *reinterpret_cast<const float2*>(Xr);
        float2 b = *reinterpret_cast<const float2*>(Xr + 512);
        float2 c = *reinterpret_cast<const float2*>(Xr + 1024);
        xr0 = a.x; xr1 = a.y; xz0 = b.x; xz1 = b.y; xpn0 = c.x; xpn1 = c.y;
      }
      const u64* Gr = ((role == 0) ? G0 : G1h) +
                      (size_t)(t & 1) * (BB * GROW) + (size_t)b_own * GROW;
      const u64* Gx = G1x + (size_t)(t & 1) * (BB * GROW) + (size_t)b_own * GROW;
      float gr0, gr1, gz0, gz1, hn0, hn1, xg0, xg1;
      for (;;) {
        u32 bad;
        u64 pr = ldA(&Gr[tid]);
        u64 pz = ldA(&Gr[tid + 256]);
        u64 pn = ldA(&Gr[tid + 512]);
        bad = ((u32)(pr >> 32) ^ want) | ((u32)(pz >> 32) ^ want) |
              ((u32)(pn >> 32) ^ want);
        u64 qr = 0, qz = 0, qx = 0;
        if (role == 1) {
          qr = ldA(&Gx[tid]);
          qz = ldA(&Gx[tid + 256]);
          qx = ldA(&Gx[tid + 512]);
          bad |= ((u32)(qr >> 32) ^ want) | ((u32)(qz >> 32) ^ want) |
                 ((u32)(qx >> 32) ^ want);
        }
        if (!bad) {
          gr0 = f16lo((u32)pr); gr1 = f16hi((u32)pr);
          gz0 = f16lo((u32)pz); gz1 = f16hi((u32)pz);
          hn0 = f16lo((u32)pn); hn1 = f16hi((u32)pn);
          if (role == 1) {
            gr0 += f16lo((u32)qr); gr1 += f16hi((u32)qr);
            gz0 += f16lo((u32)qz); gz1 += f16hi((u32)qz);
            xg0 = f16lo((u32)qx); xg1 = f16hi((u32)qx);
          } else {
            gr0 += xr0; gr1 += xr1; gz0 += xz0; gz1 += xz1;
            xg0 = xpn0; xg1 = xpn1;
          }
          break;
        }
        __builtin_amdgcn_s_sleep(1);
      }
      // LN r & z (one cross-wave combine)
      float sr = red64_(gr0 + gr1), sr2 = red64_(gr0 * gr0 + gr1 * gr1);
      float sz = red64_(gz0 + gz1), sz2 = red64_(gz0 * gz0 + gz1 * gz1);
      if (lane == 0) {
        red4[wave][0] = sr; red4[wave][1] = sr2;
        red4[wave][2] = sz; red4[wave][3] = sz2;
      }
      __syncthreads();
      float tsr = 0, tsr2 = 0, tsz = 0, tsz2 = 0;
#pragma unroll
      for (int w = 0; w < 4; ++w) {
        tsr += red4[w][0]; tsr2 += red4[w][1];
        tsz += red4[w][2]; tsz2 += red4[w][3];
      }
      const float mr = tsr * (1.f / 512.f);
      const float rsr = rsqrtf(tsr2 * (1.f / 512.f) - mr * mr + LNEPS);
      const float mz = tsz * (1.f / 512.f);
      const float rsz = rsqrtf(tsz2 * (1.f / 512.f) - mz * mz + LNEPS);
      const float rv0 = sigmoidf_((gr0 - mr) * rsr * lwv[0] + lbv[0]);
      const float rv1 = sigmoidf_((gr1 - mr) * rsr * lwv[1] + lbv[1]);
      const float zv0 = sigmoidf_((gz0 - mz) * rsz * lwv[2] + lbv[2]);
      const float zv1 = sigmoidf_((gz1 - mz) * rsz * lwv[3] + lbv[3]);
      // LN n (second combine, disjoint red4 slots)
      const float np0 = xg0 + rv0 * hn0;
      const float np1 = xg1 + rv1 * hn1;
      float sn = red64_(np0 + np1), sn2 = red64_(np0 * np0 + np1 * np1);
      if (lane == 0) { red4[wave][4] = sn; red4[wave][5] = sn2; }
      __syncthreads();
      float tn = red4[0][4] + red4[1][4] + red4[2][4] + red4[3][4];
      float tn2 = red4[0][5] + red4[1][5] + red4[2][5] + red4[3][5];
      const float mn = tn * (1.f / 512.f);
      const float rsn = rsqrtf(tn2 * (1.f / 512.f) - mn * mn + LNEPS);
      // h update (hold = h(t-1) from local LDS copy)
      u32 hp = *reinterpret_cast<const u32*>(
          &shA[b_own][physp(tid >> 2) * 8 + 2 * (tid & 3)]);
      const float n0 = tanhf_((np0 - mn) * rsn * lwv[4] + lbv[4]);
      const float n1 = tanhf_((np1 - mn) * rsn * lwv[5] + lbv[5]);
      float hv0 = (1.f - zv0) * n0 + zv0 * f16lo(hp);
      float hv1 = (1.f - zv1) * n1 + zv1 * f16hi(hp);
      if (role == 1) {  // residual h0(t): poll row flag once, then read
        while (ldA32(&h0f[(size_t)b_own * FL]) < want) __builtin_amdgcn_s_sleep(1);
        u32 r0 = ldA32(&Hb0[(size_t)(t & (H0D - 1)) * (BB * HROWU) +
                            (size_t)b_own * HROWU + tid]);
        hv0 += f16lo(r0); hv1 += f16hi(r0);
        *reinterpret_cast<float2*>(&out[((size_t)b_own * TT + t) * 512 + 2 * tid]) =
            make_float2(hv0, hv1);
      }
      // owner-0 ring throttle (per-thread, any h1f[b] >= t-7 suffices)
      if (role == 0 && t >= H0D) {
        const u32 w2 = (u32)(t - (H0D - 1));
        while (ldA32(&h1f[(size_t)(tid & 15) * FL]) < w2) __builtin_amdgcn_s_sleep(1);
      }
      // publish h row (untagged pairs) + drain + row flag
      u32* Hw = ((role == 0)
                     ? Hb0 + (size_t)(t & (H0D - 1)) * (BB * HROWU)
                     : Hb1 + (size_t)(t & (H1D - 1)) * (BB * HROWU)) +
                (size_t)b_own * HROWU;
      stA32(&Hw[tid], pkh2(hv0, hv1));
      asm volatile("s_waitcnt vmcnt(0)" ::: "memory");
      __syncthreads();
      if (tid == 0) stA32(&((role == 0) ? h0f : h1f)[(size_t)b_own * FL], want);
    }
  }
}

// ---------------- launch ----------------
extern "C" void kernel_launch(void* const* d_in, const int* in_sizes, int n_in,
                              void* d_out, int out_size, void* d_ws, size_t ws_size,
                              hipStream_t stream) {
  (void)in_sizes; (void)n_in; (void)out_size; (void)ws_size;
  const float* x   = (const float*)d_in[0];
  const float* Wi  = (const float*)d_in[1];  // [2][1536][512]
  const float* Wh  = (const float*)d_in[2];  // [2][1536][512]
  const float* lnw = (const float*)d_in[3];  // [2][3][512]
  const float* lnb = (const float*)d_in[4];
  float* out = (float*)d_out;

  float* X0 = (float*)d_ws;                     // [24000][1536] f32
  u64* G0   = (u64*)(X0 + (size_t)GM * NG3);    // [2][16][768]
  u64* G1h  = G0 + 2 * BB * GROW;               // [2][16][768]
  u64* G1x  = G1h + 2 * BB * GROW;              // [2][16][768]
  u32* Hb0  = (u32*)(G1x + 2 * BB * GROW);      // [8][16][256]
  u32* Hb1  = Hb0 + (size_t)H0D * BB * HROWU;   // [4][16][256]
  u32* flags = Hb1 + (size_t)H1D * BB * HROWU;  // 32 flag lines

  size_t clear_bytes = (size_t)(3 * 2 * BB * GROW) * 8 +
                       (size_t)((H0D + H1D) * BB * HROWU + 32 * FL) * 4;
  hipMemsetAsync(G0, 0, clear_bytes, stream);

  dim3 ggrid(GM / 64, NG3 / 64);
  gemm_nt<<<ggrid, 256, 0, stream>>>(x, Wi, X0);  // layer-0 input gates
  gru_fused<<<3 * NWG, 256, 0, stream>>>(
      Wh, Wi + (size_t)NG3 * 512, Wh + (size_t)NG3 * 512, X0, lnw, lnb, out,
      G0, G1h, G1x, Hb0, Hb1, flags);
}